// Round 8
// baseline (145.168 us; speedup 1.0000x reference)
//
#include <hip/hip_runtime.h>
#include <hip/hip_bf16.h>

#define D 128
#define TPB 8                          // 32-row tiles per block
#define NBUF 3                         // LDS ring buffers (depth-2, R4-proven)
#define TILE_BYTES (32 * D * 4)        // 16384
#define ROWS_PER_BLOCK (32 * TPB)      // 256 -> grid 512

typedef __attribute__((ext_vector_type(8))) short short8;
typedef __attribute__((ext_vector_type(4))) float float4_t;

typedef const __attribute__((address_space(1))) void g_void;
typedef __attribute__((address_space(3))) void l_void;

__device__ __forceinline__ short8 cvt8_bf16(float4_t a, float4_t b) {
    union { short8 s; __hip_bfloat16 h[8]; } u;
    u.h[0] = __float2bfloat16(a[0]);
    u.h[1] = __float2bfloat16(a[1]);
    u.h[2] = __float2bfloat16(a[2]);
    u.h[3] = __float2bfloat16(a[3]);
    u.h[4] = __float2bfloat16(b[0]);
    u.h[5] = __float2bfloat16(b[1]);
    u.h[6] = __float2bfloat16(b[2]);
    u.h[7] = __float2bfloat16(b[3]);
    return u.s;
}

// ---------------------------------------------------------------------------
// SINGLE kernel: y[m][f] = sum_d x[m][d] * (sum_o wts[o] W[o][f][d]) + bias
// M = B*S = 131072.
//
// R8 change vs R4 (session best, 121.1us): the combine dispatch is FOLDED
// into the gemm prologue. Each block loads the 4 candidate W fragments for
// its columns directly (W = 256KB, L2/L3-hot after first touch; fetched
// from HBM ~once device-wide) and reduces them in-register with wts.
// Deletes one dispatch + its graph gap + the Wc workspace round-trip.
// The gemm BODY (tiling, staging, vmcnt schedule, barriers) is byte-
// identical to R4 — clean A/B on the dispatch-count axis.
//
// R4 body recap: 256 thr = 4 waves = 2 row-halves x 2 col-halves of each
// 32-row x-tile; async global_load_lds staging, NBUF=3 ring, depth-2
// prefetch, counted vmcnt {8,12,16,16,16,16,12,8} (never 0 mid-loop),
// two s_barriers per step. LDS swizzle both-sides (linear gll dest,
// pre-XORed global source slot, XORed ds_read) -> 0 bank conflicts
// (measured R3/R4/R6).
// ---------------------------------------------------------------------------
__global__ __launch_bounds__(256, 1) void gemm_kernel(const float* __restrict__ x,
                                                      const float* __restrict__ W,
                                                      const float* __restrict__ bvec,
                                                      const float* __restrict__ wts,
                                                      float* __restrict__ y, int M) {
    __shared__ __align__(16) char Bs[NBUF * TILE_BYTES];   // 49152 B

    const int tid  = threadIdx.x;
    const int lane = tid & 63;
    const int wave = tid >> 6;
    const int r    = lane & 15;
    const int quad = lane >> 4;
    const int hb   = wave & 1;    // row-half of the 32-row tile
    const int ch   = wave >> 1;   // col-half (64 of 128 f-columns)

    const int row0 = blockIdx.x * ROWS_PER_BLOCK;
    if (row0 >= M) return;
    const float* xblk = x + (size_t)row0 * D;

    // uniform path weights (scalar loads)
    const float w0 = wts[0], w1 = wts[1], w2 = wts[2], w3 = wts[3];

    // ---- combined Wc fragments -> registers, folded from 4 candidates ----
    // (one-time; W is L2/L3-hot; these VMEM ops are OLDER than all stages,
    //  so they retire before any counted vwait below — audit intact)
    short8 wf[4][4];
    #pragma unroll
    for (int f = 0; f < 4; f++) {
        #pragma unroll
        for (int ks = 0; ks < 4; ks++) {
            const float* p = W + (size_t)(ch * 64 + f * 16 + r) * D + ks * 32 + quad * 8;
            float4_t a = w0 * *(const float4_t*)(p)
                       + w1 * *(const float4_t*)(p + D * D)
                       + w2 * *(const float4_t*)(p + 2 * D * D)
                       + w3 * *(const float4_t*)(p + 3 * D * D);
            float4_t b = w0 * *(const float4_t*)(p + 4)
                       + w1 * *(const float4_t*)(p + D * D + 4)
                       + w2 * *(const float4_t*)(p + 2 * D * D + 4)
                       + w3 * *(const float4_t*)(p + 3 * D * D + 4);
            wf[f][ks] = cvt8_bf16(a, b);
        }
    }

    // ---- combined bias -> registers ----
    float4_t bias[4];
    #pragma unroll
    for (int f = 0; f < 4; f++) {
        const float* q = bvec + ch * 64 + f * 16 + quad * 4;
        bias[f] = w0 * *(const float4_t*)(q)
                + w1 * *(const float4_t*)(q + D)
                + w2 * *(const float4_t*)(q + 2 * D)
                + w3 * *(const float4_t*)(q + 3 * D);
    }

    // ---- per-lane swizzled LDS read offsets (slot = ks*8 + quad*2 + h) ----
    int dsoff[4][2];
    #pragma unroll
    for (int ks = 0; ks < 4; ks++)
        #pragma unroll
        for (int h = 0; h < 2; h++)
            dsoff[ks][h] = (hb * 16 + r) * 512
                         + (((ks * 8 + quad * 2 + h) ^ (r & 7)) << 4);

    // stage one 32-row tile -> ring buffer: 4 gll x16B per thread, linear
    // dest (wave-uniform + lane*16), pre-swizzled global source.
#define STAGE(t) {                                                              \
        const char* tb = (const char*)(xblk + (t) * 32 * D);                    \
        char* db = Bs + ((t) % NBUF) * TILE_BYTES;                              \
        _Pragma("unroll")                                                       \
        for (int g = 0; g < 4; g++) {                                           \
            int R  = g * 8 + (tid >> 5);                                        \
            int sl = tid & 31;                                                  \
            const char* src = tb + R * 512 + ((sl ^ (R & 7)) << 4);             \
            __builtin_amdgcn_global_load_lds((g_void*)src,                      \
                (l_void*)(db + g * 4096 + (tid >> 6) * 1024), 16, 0, 0);        \
        }                                                                       \
    }

    // ---- prologue: depth-2 ----
    STAGE(0)
    STAGE(1)

    // vmcnt audit (identical to R4; W/bias loads are older and thus
    // guaranteed-retired at any counted wait): N = {8,12,16,16,16,16,12,8}.
#define STEP(T, NW) {                                                           \
        if ((T) + 2 < TPB) STAGE((T) + 2)                                       \
        asm volatile("s_waitcnt vmcnt(%0)" :: "i"(NW) : "memory");              \
        __builtin_amdgcn_sched_barrier(0);                                      \
        __builtin_amdgcn_s_barrier();                                           \
        const char* buf = Bs + ((T) % NBUF) * TILE_BYTES;                       \
        short8 xf[4];                                                           \
        _Pragma("unroll")                                                       \
        for (int ks = 0; ks < 4; ks++) {                                        \
            float4_t a0 = *(const float4_t*)(buf + dsoff[ks][0]);               \
            float4_t a1 = *(const float4_t*)(buf + dsoff[ks][1]);               \
            xf[ks] = cvt8_bf16(a0, a1);                                         \
        }                                                                       \
        asm volatile("s_waitcnt lgkmcnt(0)" ::: "memory");                      \
        __builtin_amdgcn_sched_barrier(0);                                      \
        __builtin_amdgcn_s_barrier();  /* buf rewritten from step T+1 on */     \
        float4_t acc[4];                                                        \
        _Pragma("unroll")                                                       \
        for (int f = 0; f < 4; f++) acc[f] = bias[f];                           \
        _Pragma("unroll")                                                       \
        for (int ks = 0; ks < 4; ks++) {                                        \
            _Pragma("unroll")                                                   \
            for (int f = 0; f < 4; f++)                                         \
                acc[f] = __builtin_amdgcn_mfma_f32_16x16x32_bf16(               \
                    wf[f][ks], xf[ks], acc[f], 0, 0, 0);                        \
        }                                                                       \
        float* yp = y + (size_t)(row0 + (T) * 32 + hb * 16 + r) * D             \
                      + ch * 64 + quad * 4;                                     \
        _Pragma("unroll")                                                       \
        for (int f = 0; f < 4; f++)                                             \
            *(float4_t*)(yp + f * 16) = acc[f];                                 \
    }

    STEP(0, 8)
    STEP(1, 12)
    STEP(2, 16)
    STEP(3, 16)
    STEP(4, 16)
    STEP(5, 16)
    STEP(6, 12)
    STEP(7, 8)
#undef STEP
#undef STAGE
}

extern "C" void kernel_launch(void* const* d_in, const int* in_sizes, int n_in,
                              void* d_out, int out_size, void* d_ws, size_t ws_size,
                              hipStream_t stream) {
    const float* x   = (const float*)d_in[0];   // (B,S,D) fp32
    const float* W   = (const float*)d_in[1];   // (NOPS,D,D) fp32
    const float* b   = (const float*)d_in[2];   // (NOPS,D) fp32
    const float* wts = (const float*)d_in[3];   // (NOPS,) fp32
    float* y = (float*)d_out;

    (void)d_ws; (void)ws_size;  // workspace no longer needed

    const int M = in_sizes[0] / D;  // B*S = 131072
    gemm_kernel<<<M / ROWS_PER_BLOCK, 256, 0, stream>>>(x, W, b, wts, y, M);
}

// Round 9
// 123.968 us; speedup vs baseline: 1.1710x; 1.1710x over previous
//
#include <hip/hip_runtime.h>
#include <hip/hip_bf16.h>

#define D 128
#define TILE_ROWS 32
#define TPB 8                         // tiles per block
#define NBUF 3                        // LDS ring buffers
#define TILE_BYTES (TILE_ROWS * D * 4)        // 16384
#define ROWS_PER_BLOCK (TILE_ROWS * TPB)      // 256 -> grid 512

typedef __attribute__((ext_vector_type(8))) short short8;
typedef __attribute__((ext_vector_type(4))) float float4_t;

typedef const __attribute__((address_space(1))) void g_void;
typedef __attribute__((address_space(3))) void l_void;

// ---------------------------------------------------------------------------
// Kernel 1: fold the 4 candidate ops into one combined matrix/bias.
// (R8 proved folding this into the gemm costs ~24us of serial prologue;
//  the separate tiny dispatch is the right structure.)
// ---------------------------------------------------------------------------
__global__ void combine_kernel(const float* __restrict__ W,
                               const float* __restrict__ b,
                               const float* __restrict__ wts,
                               __hip_bfloat16* __restrict__ Wc,
                               float* __restrict__ bc) {
    int idx = blockIdx.x * blockDim.x + threadIdx.x;
    float w0 = wts[0], w1 = wts[1], w2 = wts[2], w3 = wts[3];
    if (idx < D * D) {
        float v = w0 * W[idx] + w1 * W[D * D + idx]
                + w2 * W[2 * D * D + idx] + w3 * W[3 * D * D + idx];
        Wc[idx] = __float2bfloat16(v);
    }
    if (idx < D) {
        bc[idx] = w0 * b[idx] + w1 * b[D + idx] + w2 * b[2 * D + idx] + w3 * b[3 * D + idx];
    }
}

__device__ __forceinline__ short8 cvt8_bf16(float4_t a, float4_t b) {
    union { short8 s; __hip_bfloat16 h[8]; } u;
    u.h[0] = __float2bfloat16(a[0]);
    u.h[1] = __float2bfloat16(a[1]);
    u.h[2] = __float2bfloat16(a[2]);
    u.h[3] = __float2bfloat16(a[3]);
    u.h[4] = __float2bfloat16(b[0]);
    u.h[5] = __float2bfloat16(b[1]);
    u.h[6] = __float2bfloat16(b[2]);
    u.h[7] = __float2bfloat16(b[3]);
    return u.s;
}

// ---------------------------------------------------------------------------
// Kernel 2: y[m][f] = sum_d x[m][d] * Wc[f][d] + bc[f]   (M = 131072)
//
// Body is BYTE-IDENTICAL to R4 (session best, 121.1us total, gemm ~33us)
// except the y stores are NONTEMPORAL. Mechanism: R8's direct counters
// showed FETCH=33.5MB << 64MiB x (L3 serves half of x across graph
// iterations). y (64MiB, never re-read) allocating in L3 is what evicts
// the other half of x. NT stores (evict-first) keep x L3-resident ->
// stage waits on the pipeline's critical path become L3 hits (~200cy)
// instead of HBM misses (~900+cy).
//
// R4 recap: 256 thr = 4 waves = 2 row-halves x 2 col-halves per 32-row
// tile; async global_load_lds staging (linear dest, pre-XORed global
// source slot, XORed ds_read — both-sides swizzle), NBUF=3 ring, depth-2
// prefetch, counted vmcnt {8,12,16,16,16,16,12,8} (never 0 mid-loop),
// two s_barriers per step.
// ---------------------------------------------------------------------------
__global__ __launch_bounds__(256, 1) void gemm_kernel(const float* __restrict__ x,
                                                      const __hip_bfloat16* __restrict__ Wc,
                                                      const float* __restrict__ bc,
                                                      float* __restrict__ y, int M) {
    __shared__ __align__(16) char Bs[NBUF * TILE_BYTES];   // 49152 B

    const int tid  = threadIdx.x;
    const int lane = tid & 63;
    const int wave = tid >> 6;
    const int r    = lane & 15;
    const int quad = lane >> 4;
    const int hb   = wave & 1;    // row-half of the 32-row tile
    const int ch   = wave >> 1;   // col-half (64 of 128 f-columns)

    const int row0 = blockIdx.x * ROWS_PER_BLOCK;
    if (row0 >= M) return;
    const float* xblk = x + (size_t)row0 * D;

    // ---- Wc fragments + bias -> registers (older than all stages) ----
    short8 wf[4][4];
    #pragma unroll
    for (int f = 0; f < 4; f++)
        #pragma unroll
        for (int ks = 0; ks < 4; ks++)
            wf[f][ks] = *(const short8*)((const short*)Wc
                          + (ch * 64 + f * 16 + r) * D + ks * 32 + quad * 8);

    float4_t bias[4];
    #pragma unroll
    for (int f = 0; f < 4; f++)
        bias[f] = *(const float4_t*)(bc + ch * 64 + f * 16 + quad * 4);

    // ---- per-lane swizzled LDS read offsets (slot = ks*8 + quad*2 + h) ----
    int dsoff[4][2];
    #pragma unroll
    for (int ks = 0; ks < 4; ks++)
        #pragma unroll
        for (int h = 0; h < 2; h++)
            dsoff[ks][h] = (hb * 16 + r) * 512
                         + (((ks * 8 + quad * 2 + h) ^ (r & 7)) << 4);

    // stage one 32-row tile -> ring buffer: 4 gll x16B per thread, linear
    // dest (wave-uniform + lane*16), pre-swizzled global source.
#define STAGE(t) {                                                              \
        const char* tb = (const char*)(xblk + (t) * TILE_ROWS * D);             \
        char* db = Bs + ((t) % NBUF) * TILE_BYTES;                              \
        _Pragma("unroll")                                                       \
        for (int g = 0; g < 4; g++) {                                           \
            int R  = g * 8 + (tid >> 5);                                        \
            int sl = tid & 31;                                                  \
            const char* src = tb + R * 512 + ((sl ^ (R & 7)) << 4);             \
            __builtin_amdgcn_global_load_lds((g_void*)src,                      \
                (l_void*)(db + g * 4096 + (tid >> 6) * 1024), 16, 0, 0);        \
        }                                                                       \
    }

    // ---- prologue: depth-2 ----
    STAGE(0)
    STAGE(1)

    // vmcnt audit (in-order retirement): at step T's vwait, ops younger than
    // stage(T) = 4*min(2,7-T) stages + 4*min(T,2) store batches:
    // N = {8,12,16,16,16,16,12,8}. Counted, never 0 mid-loop.
#define STEP(T, NW) {                                                           \
        if ((T) + 2 < TPB) STAGE((T) + 2)                                       \
        asm volatile("s_waitcnt vmcnt(%0)" :: "i"(NW) : "memory");              \
        __builtin_amdgcn_sched_barrier(0);                                      \
        __builtin_amdgcn_s_barrier();                                           \
        const char* buf = Bs + ((T) % NBUF) * TILE_BYTES;                       \
        short8 xf[4];                                                           \
        _Pragma("unroll")                                                       \
        for (int ks = 0; ks < 4; ks++) {                                        \
            float4_t a0 = *(const float4_t*)(buf + dsoff[ks][0]);               \
            float4_t a1 = *(const float4_t*)(buf + dsoff[ks][1]);               \
            xf[ks] = cvt8_bf16(a0, a1);                                         \
        }                                                                       \
        asm volatile("s_waitcnt lgkmcnt(0)" ::: "memory");                      \
        __builtin_amdgcn_sched_barrier(0);                                      \
        __builtin_amdgcn_s_barrier();  /* buf may be overwritten next iter */   \
        float4_t acc[4];                                                        \
        _Pragma("unroll")                                                       \
        for (int f = 0; f < 4; f++) acc[f] = (float4_t)(0.f);                   \
        _Pragma("unroll")                                                       \
        for (int ks = 0; ks < 4; ks++) {                                        \
            _Pragma("unroll")                                                   \
            for (int f = 0; f < 4; f++)                                         \
                acc[f] = __builtin_amdgcn_mfma_f32_16x16x32_bf16(               \
                    wf[f][ks], xf[ks], acc[f], 0, 0, 0);                        \
        }                                                                       \
        float* yp = y + (size_t)(row0 + (T) * TILE_ROWS + hb * 16 + r) * D      \
                      + ch * 64 + quad * 4;                                     \
        _Pragma("unroll")                                                       \
        for (int f = 0; f < 4; f++) {                                           \
            float4_t out;                                                       \
            out[0] = acc[f][0] + bias[f][0];                                    \
            out[1] = acc[f][1] + bias[f][1];                                    \
            out[2] = acc[f][2] + bias[f][2];                                    \
            out[3] = acc[f][3] + bias[f][3];                                    \
            __builtin_nontemporal_store(out, (float4_t*)(yp + f * 16));         \
        }                                                                       \
    }

    STEP(0, 8)
    STEP(1, 12)
    STEP(2, 16)
    STEP(3, 16)
    STEP(4, 16)
    STEP(5, 16)
    STEP(6, 12)
    STEP(7, 8)
#undef STEP
#undef STAGE
}

extern "C" void kernel_launch(void* const* d_in, const int* in_sizes, int n_in,
                              void* d_out, int out_size, void* d_ws, size_t ws_size,
                              hipStream_t stream) {
    const float* x   = (const float*)d_in[0];   // (B,S,D) fp32
    const float* W   = (const float*)d_in[1];   // (NOPS,D,D) fp32
    const float* b   = (const float*)d_in[2];   // (NOPS,D) fp32
    const float* wts = (const float*)d_in[3];   // (NOPS,) fp32
    float* y = (float*)d_out;

    __hip_bfloat16* Wc = (__hip_bfloat16*)d_ws;
    float* bc = (float*)((char*)d_ws + D * D * sizeof(__hip_bfloat16));

    combine_kernel<<<(D * D + 255) / 256, 256, 0, stream>>>(W, b, wts, Wc, bc);

    const int M = in_sizes[0] / D;  // B*S = 131072
    gemm_kernel<<<M / ROWS_PER_BLOCK, 256, 0, stream>>>(x, Wc, bc, y, M);
}